// Round 8
// baseline (140.371 us; speedup 1.0000x reference)
//
#include <hip/hip_runtime.h>
#include <hip/hip_bf16.h>

constexpr int NN  = 4096;       // n_node + 1 == batch
constexpr int DE  = 32;         // d_emb
constexpr int TD  = 2048;       // T*D
constexpr int HS  = 272;        // padded head stride (ushorts) for Kb/Qb/Vb

typedef __attribute__((ext_vector_type(8))) short short8;
typedef __attribute__((ext_vector_type(4))) float f32x4;

#define MFMA16(a, b, c) __builtin_amdgcn_mfma_f32_16x16x32_bf16(a, b, c, 0, 0, 0)

__device__ inline ushort f2b(float x) {
    __hip_bfloat16 h = __float2bfloat16(x);
    union { __hip_bfloat16 h; ushort u; } c; c.h = h;
    return c.u;
}

__device__ inline float b2f(ushort u) {
    union { unsigned u; float f; } c; c.u = ((unsigned)u) << 16;
    return c.f;
}

__device__ inline short8 pack8(float4 a, float4 b) {
    short8 v;
    v[0] = (short)f2b(a.x); v[1] = (short)f2b(a.y); v[2] = (short)f2b(a.z); v[3] = (short)f2b(a.w);
    v[4] = (short)f2b(b.x); v[5] = (short)f2b(b.y); v[6] = (short)f2b(b.z); v[7] = (short)f2b(b.w);
    return v;
}

// ================= k_prep: s | embbf | WeTT | W cvt x3 | bnode =================
__global__ __launch_bounds__(256) void k_prep(const float* __restrict__ emb,
                                              const float* __restrict__ We,
                                              const float* __restrict__ be,
                                              const float* __restrict__ Wk,
                                              const float* __restrict__ Wv,
                                              const float* __restrict__ Wo,
                                              float* __restrict__ s_g,
                                              ushort* __restrict__ embbf,
                                              ushort* __restrict__ WeTT,
                                              ushort* __restrict__ Wkbf,
                                              ushort* __restrict__ Wvbf,
                                              ushort* __restrict__ Wobf,
                                              float* __restrict__ bn) {
    int id = blockIdx.x, tid = threadIdx.x;
    if (id < 16) {                                   // ---- s[n]
        int n = id * 256 + tid;
        const float4* e4 = (const float4*)(emb + n * DE);
        float s = 0.f;
#pragma unroll
        for (int i = 0; i < DE / 4; ++i) { float4 v = e4[i]; s += v.x + v.y + v.z + v.w; }
        s_g[n] = s;
    } else if (id < 144) {                           // ---- embbf (vectorized)
        int g4 = (id - 16) * 256 + tid;              // 0..32767
        float4 v = *(const float4*)&emb[(size_t)g4 * 4];
        ushort4 o; o.x = f2b(v.x); o.y = f2b(v.y); o.z = f2b(v.z); o.w = f2b(v.w);
        *(ushort4*)&embbf[(size_t)g4 * 4] = o;
    } else if (id < 656) {                           // ---- WeTT[od][e] = We[e][d*64+o]
        int gid = (id - 144) * 256 + tid;            // 0..131071
        int od = gid >> 5, e = gid & 31;
        int o = od >> 6, d = od & 63;
        WeTT[gid] = f2b(We[(size_t)e * 4096 + d * 64 + o]);
    } else if (id < 704) {                           // ---- Wk/Wv/Wo bf16
        int id5 = id - 656;
        int which = id5 >> 4, gid = (id5 & 15) * 256 + tid;   // 0..4095
        const float* src = which == 0 ? Wk : (which == 1 ? Wv : Wo);
        ushort* dst = which == 0 ? Wkbf : (which == 1 ? Wvbf : Wobf);
        dst[gid] = f2b(src[gid]);
    } else {                                         // ---- bnode
        int gid = (id - 704) * 256 + tid;            // 0..262143
        int n = gid >> 6, o = gid & 63;
        float acc = 0.f;
#pragma unroll
        for (int e = 0; e < DE; ++e) acc += emb[n * DE + e] * be[e * 64 + o];
        bn[gid] = acc;
    }
}

// ================= k_pr: projm(q)->bf16 [0,512) | rank [512,1024) =================
__global__ __launch_bounds__(256) void k_pr(const float* __restrict__ X,
                                            const float* __restrict__ W,
                                            const float* __restrict__ bias,
                                            ushort* __restrict__ Y,
                                            const float* __restrict__ s_g,
                                            int* __restrict__ perm) {
    __shared__ float ss[NN];
    int id = blockIdx.x, tid = threadIdx.x;
    if (id < 512) {
        int lane = tid & 63, wid = tid >> 6;
        int r0 = id * 256 + wid * 64;
        int l15 = lane & 15, kb = lane >> 4;
        f32x4 acc[4][4] = {};
#pragma unroll
        for (int kk = 0; kk < 2; ++kk) {
            short8 af[4], bf[4];
#pragma unroll
            for (int f = 0; f < 4; ++f) {
                const float* ap = X + (size_t)(r0 + f * 16 + l15) * 64 + kk * 32 + kb * 8;
                af[f] = pack8(*(const float4*)ap, *(const float4*)(ap + 4));
                const float* bp = W + (size_t)(f * 16 + l15) * 64 + kk * 32 + kb * 8;
                bf[f] = pack8(*(const float4*)bp, *(const float4*)(bp + 4));
            }
#pragma unroll
            for (int i = 0; i < 4; ++i)
#pragma unroll
                for (int j = 0; j < 4; ++j)
                    acc[i][j] = MFMA16(af[i], bf[j], acc[i][j]);
        }
        float bcol[4];
#pragma unroll
        for (int j = 0; j < 4; ++j) bcol[j] = bias[j * 16 + l15];
#pragma unroll
        for (int i = 0; i < 4; ++i)
#pragma unroll
            for (int j = 0; j < 4; ++j)
#pragma unroll
                for (int r = 0; r < 4; ++r)
                    Y[(size_t)(r0 + i * 16 + kb * 4 + r) * 64 + j * 16 + l15] =
                        f2b(acc[i][j][r] + bcol[j]);
    } else {
        for (int i = tid; i < NN; i += 256) ss[i] = s_g[i];
        __syncthreads();
        int g = tid >> 5, l = tid & 31;
        int n = (id - 512) * 8 + g;
        float sn = ss[n];
        int cnt = 0;
        for (int j2 = 0; j2 < 128; ++j2) {
            int m = j2 * 32 + l;
            float sm = ss[m];
            cnt += (sm < sn) || (sm == sn && m < n);
        }
        for (int off = 16; off; off >>= 1) cnt += __shfl_down(cnt, off, 32);
        if (l == 0) perm[cnt] = n;
    }
}

// ---------------- chunk sums: Cj[c][j][k] = sum_{i in chunk c} b^k * q[perm[i]][j] ------
__global__ __launch_bounds__(256) void k_csum(const ushort* __restrict__ qp,
                                              const float* __restrict__ s_g,
                                              const int* __restrict__ perm,
                                              float* __restrict__ Cj,
                                              float* __restrict__ Cb) {
    __shared__ int ns[64];
    __shared__ float bs[64];
    int bx = blockIdx.x, by = blockIdx.y, tid = threadIdx.x;
    if (tid < 64) {
        int n = perm[bx * 64 + tid];
        ns[tid] = n;
        bs[tid] = __expf(-s_g[n]);
    }
    __syncthreads();
    int j = by * 256 + tid;
    float run[8] = {};
    for (int ii = 0; ii < 64; ++ii) {
        float qv = b2f(qp[(size_t)ns[ii] * 2048 + j]);
        float b = bs[ii], t = qv;
#pragma unroll
        for (int k2 = 0; k2 < 8; ++k2) { run[k2] += t; t *= b; }
    }
    float* cp = Cj + ((size_t)bx * 2048 + j) * 8;
    *(float4*)cp       = make_float4(run[0], run[1], run[2], run[3]);
    *(float4*)(cp + 4) = make_float4(run[4], run[5], run[6], run[7]);
    if (by == 0 && tid < 64) {
        float b = bs[tid], bk = 1.f;
#pragma unroll
        for (int k2 = 0; k2 < 8; ++k2) {
            float v = bk;
            for (int off = 32; off; off >>= 1) v += __shfl_down(v, off, 64);
            if (tid == 0) Cb[bx * 8 + k2] = v;
            bk *= b;
        }
    }
}

// ---------------- prefix over chunks ----------------
__global__ __launch_bounds__(256) void k_pre(const float* __restrict__ Cj,
                                             float* __restrict__ PRE) {
    int gid = blockIdx.x * 256 + threadIdx.x;      // 16384
    float run = 0.f;
    for (int c = 0; c < 64; ++c) {
        PRE[(size_t)c * 16384 + gid] = run;
        run += Cj[(size_t)c * 16384 + gid];
    }
    PRE[(size_t)64 * 16384 + gid] = run;
}

// ================= k_combw: comb [0,512) | wnodem [512,1536) =================
__global__ __launch_bounds__(256) void k_combw(const ushort* __restrict__ qp,
                                               const float* __restrict__ s_g,
                                               const int* __restrict__ perm,
                                               const float* __restrict__ PRE,
                                               const float* __restrict__ Cb,
                                               ushort* __restrict__ qdifb,
                                               const ushort* __restrict__ embbf,
                                               const ushort* __restrict__ WeTT,
                                               ushort* __restrict__ WnT) {
    __shared__ int ns[64];
    __shared__ float sa[64], sb[64];
    int id = blockIdx.x, tid = threadIdx.x;
    if (id < 512) {
        int bx = id & 63, by = id >> 6;
        if (tid < 64) {
            int n = perm[bx * 64 + tid];
            ns[tid] = n;
            float s = s_g[n];
            sa[tid] = __expf(s);
            sb[tid] = __expf(-s);
        }
        __syncthreads();
        int j = by * 256 + tid;
        float T[8], pre[8];
        {
            const float* pp = PRE + (size_t)bx * 16384 + (size_t)j * 8;
            float4 u0 = *(const float4*)pp, u1 = *(const float4*)(pp + 4);
            pre[0] = u0.x; pre[1] = u0.y; pre[2] = u0.z; pre[3] = u0.w;
            pre[4] = u1.x; pre[5] = u1.y; pre[6] = u1.z; pre[7] = u1.w;
            const float* tp = PRE + (size_t)64 * 16384 + (size_t)j * 8;
            float4 t0 = *(const float4*)tp, t1 = *(const float4*)(tp + 4);
            T[0] = t0.x; T[1] = t0.y; T[2] = t0.z; T[3] = t0.w;
            T[4] = t1.x; T[5] = t1.y; T[6] = t1.z; T[7] = t1.w;
        }
        float TB[8] = {}, preb[8] = {};
        for (int c = 0; c < 64; ++c) {
            float4 v0 = *(const float4*)&Cb[c * 8], v1 = *(const float4*)&Cb[c * 8 + 4];
            TB[0] += v0.x; TB[1] += v0.y; TB[2] += v0.z; TB[3] += v0.w;
            TB[4] += v1.x; TB[5] += v1.y; TB[6] += v1.z; TB[7] += v1.w;
            if (c < bx) {
                preb[0] += v0.x; preb[1] += v0.y; preb[2] += v0.z; preb[3] += v0.w;
                preb[4] += v1.x; preb[5] += v1.y; preb[6] += v1.z; preb[7] += v1.w;
            }
        }
        for (int ii = 0; ii < 64; ++ii) {
            int n = ns[ii];
            float a = sa[ii], b = sb[ii];
            float g0 = 0.36787944117144233f;       // e^{-1}
            float g1 = g0 * a;
            float g2 = g1 * a * 0.5f;
            float g3 = g2 * a * (1.f / 3.f);
            float g4 = g3 * a * 0.25f;
            float g5 = g4 * a * 0.2f;
            float g6 = g5 * a * (1.f / 6.f);
            float g7 = g6 * a * (1.f / 7.f);
            float Z = a * preb[1]
                    + g0 * (TB[0] - preb[0]) + g1 * (TB[1] - preb[1])
                    + g2 * (TB[2] - preb[2]) + g3 * (TB[3] - preb[3])
                    + g4 * (TB[4] - preb[4]) + g5 * (TB[5] - preb[5])
                    + g6 * (TB[6] - preb[6]) + g7 * (TB[7] - preb[7]);
            float izv = 1.f / Z;
            float qv = b2f(qp[(size_t)n * 2048 + j]);
            float ss2 = g0 * (T[0] - pre[0]) + g1 * (T[1] - pre[1])
                      + g2 * (T[2] - pre[2]) + g3 * (T[3] - pre[3])
                      + g4 * (T[4] - pre[4]) + g5 * (T[5] - pre[5])
                      + g6 * (T[6] - pre[6]) + g7 * (T[7] - pre[7]);
            float outv = (a * pre[1] + ss2) * izv + qv;
            qdifb[(size_t)n * 2048 + j] = f2b(outv);
            float bk = 1.f;
#pragma unroll
            for (int k2 = 0; k2 < 8; ++k2) { pre[k2] += bk * qv; preb[k2] += bk; bk *= b; }
        }
    } else {
        int w2 = id - 512;
        int lane = tid & 63, wid = tid >> 6;
        int n0  = (w2 & 31) * 128 + (wid >> 1) * 64;
        int od0 = (w2 >> 5) * 128 + (wid & 1) * 64;
        int l15 = lane & 15, kb = lane >> 4;
        short8 af[4], bf[4];
#pragma unroll
        for (int f = 0; f < 4; ++f) {
            af[f] = *(const short8*)(embbf + (size_t)(n0 + f * 16 + l15) * 32 + kb * 8);
            bf[f] = *(const short8*)(WeTT + (size_t)(od0 + f * 16 + l15) * 32 + kb * 8);
        }
        f32x4 acc[4][4] = {};
#pragma unroll
        for (int i = 0; i < 4; ++i)
#pragma unroll
            for (int j = 0; j < 4; ++j)
                acc[i][j] = MFMA16(af[i], bf[j], acc[i][j]);
#pragma unroll
        for (int i = 0; i < 4; ++i)
#pragma unroll
            for (int j = 0; j < 4; ++j)
#pragma unroll
                for (int r = 0; r < 4; ++r)
                    WnT[(size_t)(n0 + i * 16 + kb * 4 + r) * 4096 + od0 + j * 16 + l15] =
                        f2b(acc[i][j][r]);
    }
}

// ---------------- fused: TWO batches per block (batch-level ILP), one barrier ----------
__global__ __launch_bounds__(256, 2) void k_fused(const float* __restrict__ kin,
                                                  const float* __restrict__ vin,
                                                  const ushort* __restrict__ qdifb,
                                                  const ushort* __restrict__ WnT,
                                                  const float* __restrict__ bn,
                                                  const ushort* __restrict__ Wkbf,
                                                  const float* __restrict__ bk,
                                                  const ushort* __restrict__ Wvbf,
                                                  const float* __restrict__ bv,
                                                  const ushort* __restrict__ Wobf,
                                                  const float* __restrict__ bo,
                                                  float* __restrict__ out) {
    __shared__ ushort Kb[2][8 * HS];
    __shared__ ushort Qb[2][8 * HS];
    __shared__ ushort Vb[2][8 * HS];
    __shared__ ushort attb[2][32 * 72];
    int tid = threadIdx.x, lane = tid & 63, w = tid >> 6;
    int b0 = blockIdx.x * 2;
    int l15 = lane & 15, g = lane >> 4;
    int col = w * 16 + l15;

    // ---- weight fragments (shared by both batches) ----
    short8 bkf[2], bvf[2], bof[2];
#pragma unroll
    for (int kk = 0; kk < 2; ++kk) {
        bkf[kk] = *(const short8*)(Wkbf + (size_t)col * 64 + kk * 32 + g * 8);
        bvf[kk] = *(const short8*)(Wvbf + (size_t)col * 64 + kk * 32 + g * 8);
        bof[kk] = *(const short8*)(Wobf + (size_t)col * 64 + kk * 32 + g * 8);
    }
    float bkc = bk[col], bvc = bv[col], boc = bo[col];

    // ======== phases 1+2 per batch (independent chains -> scheduler interleaves) ========
    const float SCALE = 0.35355339059327373f;   // 1/sqrt(8)
    short8 zfrag = {};
#pragma unroll
    for (int u = 0; u < 2; ++u) {
        int b = b0 + u;
        // phase 1: kp/vp/q2 projections for this batch
        f32x4 ck[2] = {}, cv[2] = {}, cq[2] = {};
#pragma unroll
        for (int kk = 0; kk < 2; ++kk) {
            short8 bqf = *(const short8*)(WnT + (size_t)b * 4096 + (size_t)col * 64 + kk * 32 + g * 8);
#pragma unroll
            for (int ti = 0; ti < 2; ++ti) {
                const float* ap = kin + (size_t)b * TD + (ti * 16 + l15) * 64 + kk * 32 + g * 8;
                short8 ak = pack8(*(const float4*)ap, *(const float4*)(ap + 4));
                const float* vp_ = vin + (size_t)b * TD + (ti * 16 + l15) * 64 + kk * 32 + g * 8;
                short8 av = pack8(*(const float4*)vp_, *(const float4*)(vp_ + 4));
                short8 aq = *(const short8*)(qdifb + (size_t)b * TD + (ti * 16 + l15) * 64 + kk * 32 + g * 8);
                ck[ti] = MFMA16(ak, bkf[kk], ck[ti]);
                cv[ti] = MFMA16(av, bvf[kk], cv[ti]);
                cq[ti] = MFMA16(aq, bqf, cq[ti]);
            }
        }
        {
            float bnc = bn[b * 64 + col];
            int h1 = col >> 3, d1 = col & 7;
#pragma unroll
            for (int ti = 0; ti < 2; ++ti) {
#pragma unroll
                for (int r = 0; r < 4; ++r) {
                    int s = ti * 16 + g * 4 + r;
                    Kb[u][h1 * HS + s * 8 + d1] = f2b(ck[ti][r] + bkc);
                    Qb[u][h1 * HS + s * 8 + d1] = f2b(cq[ti][r] + bnc);
                }
#pragma unroll
                for (int r = 0; r < 4; r += 2) {
                    int s = ti * 16 + g * 4 + r;
                    ushort2 p; p.x = f2b(cv[ti][r] + bvc); p.y = f2b(cv[ti][r + 1] + bvc);
                    *(ushort2*)&Vb[u][h1 * HS + d1 * 32 + s] = p;
                }
            }
        }
        // phase 2: per-head MFMA attention (wave w owns heads 2w,2w+1; own LDS writes)
#pragma unroll
        for (int hh = 0; hh < 2; ++hh) {
            int h = w * 2 + hh;
            short8 kf[2], qf[2];
#pragma unroll
            for (int si = 0; si < 2; ++si)
                kf[si] = (lane < 16) ? *(const short8*)&Kb[u][h * HS + (si * 16 + l15) * 8] : zfrag;
#pragma unroll
            for (int ti = 0; ti < 2; ++ti)
                qf[ti] = (lane < 16) ? *(const short8*)&Qb[u][h * HS + (ti * 16 + l15) * 8] : zfrag;
            f32x4 sc[2][2];
#pragma unroll
            for (int si = 0; si < 2; ++si)
#pragma unroll
                for (int ti = 0; ti < 2; ++ti)
                    sc[si][ti] = MFMA16(kf[si], qf[ti], f32x4{});
            unsigned pq[2][2][2];
#pragma unroll
            for (int ti = 0; ti < 2; ++ti) {
                float e0[4], e1[4], sm = 0.f;
#pragma unroll
                for (int r = 0; r < 4; ++r) {
                    e0[r] = __expf(sc[0][ti][r] * SCALE);
                    e1[r] = __expf(sc[1][ti][r] * SCALE);
                    sm += e0[r] + e1[r];
                }
                sm += __shfl_xor(sm, 16);
                sm += __shfl_xor(sm, 32);
                float inv = 1.f / sm;
                pq[0][ti][0] = (unsigned)f2b(e0[0] * inv) | ((unsigned)f2b(e0[1] * inv) << 16);
                pq[0][ti][1] = (unsigned)f2b(e0[2] * inv) | ((unsigned)f2b(e0[3] * inv) << 16);
                pq[1][ti][0] = (unsigned)f2b(e1[0] * inv) | ((unsigned)f2b(e1[1] * inv) << 16);
                pq[1][ti][1] = (unsigned)f2b(e1[2] * inv) | ((unsigned)f2b(e1[3] * inv) << 16);
            }
            short8 vf = *(const short8*)&Vb[u][h * HS + (l15 & 7) * 32 + g * 8];
            int L0 = l15 + ((g & 1) << 5);
            int L1 = L0 + 16;
            bool s1 = (g >> 1) != 0;
#pragma unroll
            for (int ti = 0; ti < 2; ++ti) {
                unsigned a00 = __shfl(pq[0][ti][0], L0), a01 = __shfl(pq[0][ti][1], L0);
                unsigned a10 = __shfl(pq[1][ti][0], L0), a11 = __shfl(pq[1][ti][1], L0);
                unsigned b00 = __shfl(pq[0][ti][0], L1), b01 = __shfl(pq[0][ti][1], L1);
                unsigned b10 = __shfl(pq[1][ti][0], L1), b11 = __shfl(pq[1][ti][1], L1);
                union { unsigned uu[4]; short8 s8; } af;
                af.uu[0] = s1 ? a10 : a00; af.uu[1] = s1 ? a11 : a01;
                af.uu[2] = s1 ? b10 : b00; af.uu[3] = s1 ? b11 : b01;
                f32x4 pv = MFMA16(af.s8, vf, f32x4{});
                if (l15 < 8) {
#pragma unroll
                    for (int r = 0; r < 4; ++r)
                        attb[u][(ti * 16 + g * 4 + r) * 72 + h * 8 + l15] = f2b(pv[r]);
                }
            }
        }
    }
    __syncthreads();

    // ======== phase 3: MFMA epilogue per batch ========
#pragma unroll
    for (int u = 0; u < 2; ++u) {
        int b = b0 + u;
        f32x4 co[2] = {};
#pragma unroll
        for (int kk = 0; kk < 2; ++kk) {
#pragma unroll
            for (int ti = 0; ti < 2; ++ti) {
                short8 aof = *(const short8*)&attb[u][(ti * 16 + l15) * 72 + kk * 32 + g * 8];
                co[ti] = MFMA16(aof, bof[kk], co[ti]);
            }
        }
#pragma unroll
        for (int ti = 0; ti < 2; ++ti)
#pragma unroll
            for (int r = 0; r < 4; ++r)
                out[(size_t)b * TD + (ti * 16 + g * 4 + r) * 64 + col] = co[ti][r] + boc;
    }
}

extern "C" void kernel_launch(void* const* d_in, const int* in_sizes, int n_in,
                              void* d_out, int out_size, void* d_ws, size_t ws_size,
                              hipStream_t stream) {
    const float* q   = (const float*)d_in[0];
    const float* k   = (const float*)d_in[1];
    const float* v   = (const float*)d_in[2];
    const float* emb = (const float*)d_in[3];
    const float* We  = (const float*)d_in[4];
    const float* be  = (const float*)d_in[5];
    const float* Wq  = (const float*)d_in[6];
    const float* bq  = (const float*)d_in[7];
    const float* Wk  = (const float*)d_in[8];
    const float* bk  = (const float*)d_in[9];
    const float* Wv  = (const float*)d_in[10];
    const float* bv  = (const float*)d_in[11];
    const float* Wo  = (const float*)d_in[12];
    const float* bo  = (const float*)d_in[13];

    float* ws = (float*)d_ws;
    ushort* qp    = (ushort*)ws;                          // 16 MB (bf16 now)
    ushort* WnT   = (ushort*)(ws + 4194304);              // 32 MB
    ushort* qdifb = (ushort*)(ws + 12582912);             // 16 MB
    float*  Cj    = ws + 16777216;                        // 4 MB
    float*  bn    = ws + 17825792;                        // 1 MB
    float*  s_g   = ws + 18087936;                        // 16 KB
    int*    perm  = (int*)(ws + 18092032);                // 16 KB
    float*  Cb    = ws + 18096128;                        // 2 KB
    ushort* embbf = (ushort*)(ws + 18096640);             // 256 KB
    ushort* WeTT  = (ushort*)(ws + 18162176);             // 256 KB
    ushort* Wkbf  = (ushort*)(ws + 18227712);             // 8 KB
    ushort* Wvbf  = (ushort*)(ws + 18229760);             // 8 KB
    ushort* Wobf  = (ushort*)(ws + 18231808);             // 8 KB
    float*  PRE   = ws + 18233856;                        // 4.25 MB (end ~78 MB)
    float*  outp  = (float*)d_out;

    k_prep <<<1728, 256, 0, stream>>>(emb, We, be, Wk, Wv, Wo,
                                      s_g, embbf, WeTT, Wkbf, Wvbf, Wobf, bn);
    k_pr   <<<1024, 256, 0, stream>>>(q, Wq, bq, qp, s_g, perm);
    k_csum <<<dim3(64, 8), 256, 0, stream>>>(qp, s_g, perm, Cj, Cb);
    k_pre  <<<64, 256, 0, stream>>>(Cj, PRE);
    k_combw<<<1536, 256, 0, stream>>>(qp, s_g, perm, PRE, Cb, qdifb,
                                      embbf, WeTT, WnT);
    k_fused<<<2048, 256, 0, stream>>>(k, v, qdifb, WnT, bn,
                                      Wkbf, bk, Wvbf, bv, Wobf, bo, outp);
}

// Round 9
// 126.233 us; speedup vs baseline: 1.1120x; 1.1120x over previous
//
#include <hip/hip_runtime.h>
#include <hip/hip_bf16.h>

constexpr int NN  = 4096;       // n_node + 1 == batch
constexpr int DE  = 32;         // d_emb
constexpr int TD  = 2048;       // T*D

typedef __attribute__((ext_vector_type(8))) short short8;
typedef __attribute__((ext_vector_type(4))) float f32x4;

#define MFMA16(a, b, c) __builtin_amdgcn_mfma_f32_16x16x32_bf16(a, b, c, 0, 0, 0)

__device__ inline ushort f2b(float x) {
    __hip_bfloat16 h = __float2bfloat16(x);
    union { __hip_bfloat16 h; ushort u; } c; c.h = h;
    return c.u;
}

__device__ inline float b2f(ushort u) {
    union { unsigned u; float f; } c; c.u = ((unsigned)u) << 16;
    return c.f;
}

__device__ inline short8 pack8(float4 a, float4 b) {
    short8 v;
    v[0] = (short)f2b(a.x); v[1] = (short)f2b(a.y); v[2] = (short)f2b(a.z); v[3] = (short)f2b(a.w);
    v[4] = (short)f2b(b.x); v[5] = (short)f2b(b.y); v[6] = (short)f2b(b.z); v[7] = (short)f2b(b.w);
    return v;
}

// ================= k_prep: s | embbf | WeTT | W cvt x3 | bnode =================
__global__ __launch_bounds__(256) void k_prep(const float* __restrict__ emb,
                                              const float* __restrict__ We,
                                              const float* __restrict__ be,
                                              const float* __restrict__ Wk,
                                              const float* __restrict__ Wv,
                                              const float* __restrict__ Wo,
                                              float* __restrict__ s_g,
                                              ushort* __restrict__ embbf,
                                              ushort* __restrict__ WeTT,
                                              ushort* __restrict__ Wkbf,
                                              ushort* __restrict__ Wvbf,
                                              ushort* __restrict__ Wobf,
                                              float* __restrict__ bn) {
    int id = blockIdx.x, tid = threadIdx.x;
    if (id < 16) {                                   // ---- s[n]
        int n = id * 256 + tid;
        const float4* e4 = (const float4*)(emb + n * DE);
        float s = 0.f;
#pragma unroll
        for (int i = 0; i < DE / 4; ++i) { float4 v = e4[i]; s += v.x + v.y + v.z + v.w; }
        s_g[n] = s;
    } else if (id < 144) {                           // ---- embbf (vectorized)
        int g4 = (id - 16) * 256 + tid;              // 0..32767
        float4 v = *(const float4*)&emb[(size_t)g4 * 4];
        ushort4 o; o.x = f2b(v.x); o.y = f2b(v.y); o.z = f2b(v.z); o.w = f2b(v.w);
        *(ushort4*)&embbf[(size_t)g4 * 4] = o;
    } else if (id < 656) {                           // ---- WeTT[od][e] = We[e][d*64+o]
        int gid = (id - 144) * 256 + tid;            // 0..131071
        int od = gid >> 5, e = gid & 31;
        int o = od >> 6, d = od & 63;
        WeTT[gid] = f2b(We[(size_t)e * 4096 + d * 64 + o]);
    } else if (id < 704) {                           // ---- Wk/Wv/Wo bf16
        int id5 = id - 656;
        int which = id5 >> 4, gid = (id5 & 15) * 256 + tid;   // 0..4095
        const float* src = which == 0 ? Wk : (which == 1 ? Wv : Wo);
        ushort* dst = which == 0 ? Wkbf : (which == 1 ? Wvbf : Wobf);
        dst[gid] = f2b(src[gid]);
    } else {                                         // ---- bnode
        int gid = (id - 704) * 256 + tid;            // 0..262143
        int n = gid >> 6, o = gid & 63;
        float acc = 0.f;
#pragma unroll
        for (int e = 0; e < DE; ++e) acc += emb[n * DE + e] * be[e * 64 + o];
        bn[gid] = acc;
    }
}

// ================= k_pr: projm(q)->bf16 [0,512) | rank [512,1024) =================
__global__ __launch_bounds__(256) void k_pr(const float* __restrict__ X,
                                            const float* __restrict__ W,
                                            const float* __restrict__ bias,
                                            ushort* __restrict__ Y,
                                            const float* __restrict__ s_g,
                                            int* __restrict__ perm) {
    __shared__ float ss[NN];
    int id = blockIdx.x, tid = threadIdx.x;
    if (id < 512) {
        int lane = tid & 63, wid = tid >> 6;
        int r0 = id * 256 + wid * 64;
        int l15 = lane & 15, kb = lane >> 4;
        f32x4 acc[4][4] = {};
#pragma unroll
        for (int kk = 0; kk < 2; ++kk) {
            short8 af[4], bf[4];
#pragma unroll
            for (int f = 0; f < 4; ++f) {
                const float* ap = X + (size_t)(r0 + f * 16 + l15) * 64 + kk * 32 + kb * 8;
                af[f] = pack8(*(const float4*)ap, *(const float4*)(ap + 4));
                const float* bp = W + (size_t)(f * 16 + l15) * 64 + kk * 32 + kb * 8;
                bf[f] = pack8(*(const float4*)bp, *(const float4*)(bp + 4));
            }
#pragma unroll
            for (int i = 0; i < 4; ++i)
#pragma unroll
                for (int j = 0; j < 4; ++j)
                    acc[i][j] = MFMA16(af[i], bf[j], acc[i][j]);
        }
        float bcol[4];
#pragma unroll
        for (int j = 0; j < 4; ++j) bcol[j] = bias[j * 16 + l15];
#pragma unroll
        for (int i = 0; i < 4; ++i)
#pragma unroll
            for (int j = 0; j < 4; ++j)
#pragma unroll
                for (int r = 0; r < 4; ++r)
                    Y[(size_t)(r0 + i * 16 + kb * 4 + r) * 64 + j * 16 + l15] =
                        f2b(acc[i][j][r] + bcol[j]);
    } else {
        for (int i = tid; i < NN; i += 256) ss[i] = s_g[i];
        __syncthreads();
        int g = tid >> 5, l = tid & 31;
        int n = (id - 512) * 8 + g;
        float sn = ss[n];
        int cnt = 0;
        for (int j2 = 0; j2 < 128; ++j2) {
            int m = j2 * 32 + l;
            float sm = ss[m];
            cnt += (sm < sn) || (sm == sn && m < n);
        }
        for (int off = 16; off; off >>= 1) cnt += __shfl_down(cnt, off, 32);
        if (l == 0) perm[cnt] = n;
    }
}

// ---------------- chunk sums: Cj[c][j][k] = sum_{i in chunk c} b^k * q[perm[i]][j] ------
__global__ __launch_bounds__(256) void k_csum(const ushort* __restrict__ qp,
                                              const float* __restrict__ s_g,
                                              const int* __restrict__ perm,
                                              float* __restrict__ Cj,
                                              float* __restrict__ Cb) {
    __shared__ int ns[64];
    __shared__ float bs[64];
    int bx = blockIdx.x, by = blockIdx.y, tid = threadIdx.x;
    if (tid < 64) {
        int n = perm[bx * 64 + tid];
        ns[tid] = n;
        bs[tid] = __expf(-s_g[n]);
    }
    __syncthreads();
    int j = by * 256 + tid;
    float run[8] = {};
    for (int ii = 0; ii < 64; ++ii) {
        float qv = b2f(qp[(size_t)ns[ii] * 2048 + j]);
        float b = bs[ii], t = qv;
#pragma unroll
        for (int k2 = 0; k2 < 8; ++k2) { run[k2] += t; t *= b; }
    }
    float* cp = Cj + ((size_t)bx * 2048 + j) * 8;
    *(float4*)cp       = make_float4(run[0], run[1], run[2], run[3]);
    *(float4*)(cp + 4) = make_float4(run[4], run[5], run[6], run[7]);
    if (by == 0 && tid < 64) {
        float b = bs[tid], bk = 1.f;
#pragma unroll
        for (int k2 = 0; k2 < 8; ++k2) {
            float v = bk;
            for (int off = 32; off; off >>= 1) v += __shfl_down(v, off, 64);
            if (tid == 0) Cb[bx * 8 + k2] = v;
            bk *= b;
        }
    }
}

// ---------------- prefix over chunks ----------------
__global__ __launch_bounds__(256) void k_pre(const float* __restrict__ Cj,
                                             float* __restrict__ PRE) {
    int gid = blockIdx.x * 256 + threadIdx.x;      // 16384
    float run = 0.f;
    for (int c = 0; c < 64; ++c) {
        PRE[(size_t)c * 16384 + gid] = run;
        run += Cj[(size_t)c * 16384 + gid];
    }
    PRE[(size_t)64 * 16384 + gid] = run;
}

// ================= k_combw: comb [0,512) | wnodem [512,1536) =================
__global__ __launch_bounds__(256) void k_combw(const ushort* __restrict__ qp,
                                               const float* __restrict__ s_g,
                                               const int* __restrict__ perm,
                                               const float* __restrict__ PRE,
                                               const float* __restrict__ Cb,
                                               ushort* __restrict__ qdifb,
                                               const ushort* __restrict__ embbf,
                                               const ushort* __restrict__ WeTT,
                                               ushort* __restrict__ WnT) {
    __shared__ int ns[64];
    __shared__ float sa[64], sb[64];
    int id = blockIdx.x, tid = threadIdx.x;
    if (id < 512) {
        int bx = id & 63, by = id >> 6;
        if (tid < 64) {
            int n = perm[bx * 64 + tid];
            ns[tid] = n;
            float s = s_g[n];
            sa[tid] = __expf(s);
            sb[tid] = __expf(-s);
        }
        __syncthreads();
        int j = by * 256 + tid;
        float T[8], pre[8];
        {
            const float* pp = PRE + (size_t)bx * 16384 + (size_t)j * 8;
            float4 u0 = *(const float4*)pp, u1 = *(const float4*)(pp + 4);
            pre[0] = u0.x; pre[1] = u0.y; pre[2] = u0.z; pre[3] = u0.w;
            pre[4] = u1.x; pre[5] = u1.y; pre[6] = u1.z; pre[7] = u1.w;
            const float* tp = PRE + (size_t)64 * 16384 + (size_t)j * 8;
            float4 t0 = *(const float4*)tp, t1 = *(const float4*)(tp + 4);
            T[0] = t0.x; T[1] = t0.y; T[2] = t0.z; T[3] = t0.w;
            T[4] = t1.x; T[5] = t1.y; T[6] = t1.z; T[7] = t1.w;
        }
        float TB[8] = {}, preb[8] = {};
        for (int c = 0; c < 64; ++c) {
            float4 v0 = *(const float4*)&Cb[c * 8], v1 = *(const float4*)&Cb[c * 8 + 4];
            TB[0] += v0.x; TB[1] += v0.y; TB[2] += v0.z; TB[3] += v0.w;
            TB[4] += v1.x; TB[5] += v1.y; TB[6] += v1.z; TB[7] += v1.w;
            if (c < bx) {
                preb[0] += v0.x; preb[1] += v0.y; preb[2] += v0.z; preb[3] += v0.w;
                preb[4] += v1.x; preb[5] += v1.y; preb[6] += v1.z; preb[7] += v1.w;
            }
        }
        for (int ii = 0; ii < 64; ++ii) {
            int n = ns[ii];
            float a = sa[ii], b = sb[ii];
            float g0 = 0.36787944117144233f;       // e^{-1}
            float g1 = g0 * a;
            float g2 = g1 * a * 0.5f;
            float g3 = g2 * a * (1.f / 3.f);
            float g4 = g3 * a * 0.25f;
            float g5 = g4 * a * 0.2f;
            float g6 = g5 * a * (1.f / 6.f);
            float g7 = g6 * a * (1.f / 7.f);
            float Z = a * preb[1]
                    + g0 * (TB[0] - preb[0]) + g1 * (TB[1] - preb[1])
                    + g2 * (TB[2] - preb[2]) + g3 * (TB[3] - preb[3])
                    + g4 * (TB[4] - preb[4]) + g5 * (TB[5] - preb[5])
                    + g6 * (TB[6] - preb[6]) + g7 * (TB[7] - preb[7]);
            float izv = 1.f / Z;
            float qv = b2f(qp[(size_t)n * 2048 + j]);
            float ss2 = g0 * (T[0] - pre[0]) + g1 * (T[1] - pre[1])
                      + g2 * (T[2] - pre[2]) + g3 * (T[3] - pre[3])
                      + g4 * (T[4] - pre[4]) + g5 * (T[5] - pre[5])
                      + g6 * (T[6] - pre[6]) + g7 * (T[7] - pre[7]);
            float outv = (a * pre[1] + ss2) * izv + qv;
            qdifb[(size_t)n * 2048 + j] = f2b(outv);
            float bk = 1.f;
#pragma unroll
            for (int k2 = 0; k2 < 8; ++k2) { pre[k2] += bk * qv; preb[k2] += bk; bk *= b; }
        }
    } else {
        int w2 = id - 512;
        int lane = tid & 63, wid = tid >> 6;
        int n0  = (w2 & 31) * 128 + (wid >> 1) * 64;
        int od0 = (w2 >> 5) * 128 + (wid & 1) * 64;
        int l15 = lane & 15, kb = lane >> 4;
        short8 af[4], bf[4];
#pragma unroll
        for (int f = 0; f < 4; ++f) {
            af[f] = *(const short8*)(embbf + (size_t)(n0 + f * 16 + l15) * 32 + kb * 8);
            bf[f] = *(const short8*)(WeTT + (size_t)(od0 + f * 16 + l15) * 32 + kb * 8);
        }
        f32x4 acc[4][4] = {};
#pragma unroll
        for (int i = 0; i < 4; ++i)
#pragma unroll
            for (int j = 0; j < 4; ++j)
                acc[i][j] = MFMA16(af[i], bf[j], acc[i][j]);
#pragma unroll
        for (int i = 0; i < 4; ++i)
#pragma unroll
            for (int j = 0; j < 4; ++j)
#pragma unroll
                for (int r = 0; r < 4; ++r)
                    WnT[(size_t)(n0 + i * 16 + kb * 4 + r) * 4096 + od0 + j * 16 + l15] =
                        f2b(acc[i][j][r]);
    }
}

// ---------------- fused: ONE WAVE = ONE BATCH; wave-private LDS; zero barriers ----------
__global__ __launch_bounds__(128, 2) void k_fused(const float* __restrict__ kin,
                                                  const float* __restrict__ vin,
                                                  const ushort* __restrict__ qdifb,
                                                  const ushort* __restrict__ WnT,
                                                  const float* __restrict__ bn,
                                                  const ushort* __restrict__ Wkbf,
                                                  const float* __restrict__ bk,
                                                  const ushort* __restrict__ Wvbf,
                                                  const float* __restrict__ bv,
                                                  const ushort* __restrict__ Wobf,
                                                  const float* __restrict__ bo,
                                                  float* __restrict__ out) {
    __shared__ ushort Kb[2][2048];      // [h][s][d]  8 x 32 x 8
    __shared__ ushort Qb[2][2048];      // [h][t][d]
    __shared__ ushort Vb[2][2048];      // [h][d][s]
    __shared__ ushort attb[2][32 * 72]; // [t][d64] stride 72
    int tid = threadIdx.x, lane = tid & 63, w = tid >> 6;
    int b = blockIdx.x * 2 + w;
    int l15 = lane & 15, g = lane >> 4;

    float bkc[4], bvc[4], bnc[4], boc[4];
#pragma unroll
    for (int j = 0; j < 4; ++j) {
        bkc[j] = bk[j * 16 + l15];
        bvc[j] = bv[j * 16 + l15];
        bnc[j] = bn[b * 64 + j * 16 + l15];
        boc[j] = bo[j * 16 + l15];
    }

    // ======== phase 1a: K projection (this wave's batch only) ========
    {
        short8 afr[2][2];
#pragma unroll
        for (int kk = 0; kk < 2; ++kk)
#pragma unroll
            for (int ti = 0; ti < 2; ++ti) {
                const float* ap = kin + (size_t)b * TD + (ti * 16 + l15) * 64 + kk * 32 + g * 8;
                afr[kk][ti] = pack8(*(const float4*)ap, *(const float4*)(ap + 4));
            }
        f32x4 acc[2][4] = {};
#pragma unroll
        for (int kk = 0; kk < 2; ++kk)
#pragma unroll
            for (int j = 0; j < 4; ++j) {
                short8 bf = *(const short8*)(Wkbf + (size_t)(j * 16 + l15) * 64 + kk * 32 + g * 8);
#pragma unroll
                for (int ti = 0; ti < 2; ++ti)
                    acc[ti][j] = MFMA16(afr[kk][ti], bf, acc[ti][j]);
            }
#pragma unroll
        for (int ti = 0; ti < 2; ++ti)
#pragma unroll
            for (int j = 0; j < 4; ++j) {
                int col = j * 16 + l15, h1 = col >> 3, d1 = col & 7;
#pragma unroll
                for (int r = 0; r < 4; ++r) {
                    int s = ti * 16 + g * 4 + r;
                    Kb[w][h1 * 256 + s * 8 + d1] = f2b(acc[ti][j][r] + bkc[j]);
                }
            }
    }
    // ======== phase 1b: Q2 projection ========
    {
        short8 afr[2][2];
#pragma unroll
        for (int kk = 0; kk < 2; ++kk)
#pragma unroll
            for (int ti = 0; ti < 2; ++ti)
                afr[kk][ti] = *(const short8*)(qdifb + (size_t)b * TD + (ti * 16 + l15) * 64 + kk * 32 + g * 8);
        f32x4 acc[2][4] = {};
#pragma unroll
        for (int kk = 0; kk < 2; ++kk)
#pragma unroll
            for (int j = 0; j < 4; ++j) {
                short8 bf = *(const short8*)(WnT + (size_t)b * 4096 + (size_t)(j * 16 + l15) * 64 + kk * 32 + g * 8);
#pragma unroll
                for (int ti = 0; ti < 2; ++ti)
                    acc[ti][j] = MFMA16(afr[kk][ti], bf, acc[ti][j]);
            }
#pragma unroll
        for (int ti = 0; ti < 2; ++ti)
#pragma unroll
            for (int j = 0; j < 4; ++j) {
                int col = j * 16 + l15, h1 = col >> 3, d1 = col & 7;
#pragma unroll
                for (int r = 0; r < 4; ++r) {
                    int s = ti * 16 + g * 4 + r;
                    Qb[w][h1 * 256 + s * 8 + d1] = f2b(acc[ti][j][r] + bnc[j]);
                }
            }
    }
    // ======== phase 1c: V projection ========
    {
        short8 afr[2][2];
#pragma unroll
        for (int kk = 0; kk < 2; ++kk)
#pragma unroll
            for (int ti = 0; ti < 2; ++ti) {
                const float* ap = vin + (size_t)b * TD + (ti * 16 + l15) * 64 + kk * 32 + g * 8;
                afr[kk][ti] = pack8(*(const float4*)ap, *(const float4*)(ap + 4));
            }
        f32x4 acc[2][4] = {};
#pragma unroll
        for (int kk = 0; kk < 2; ++kk)
#pragma unroll
            for (int j = 0; j < 4; ++j) {
                short8 bf = *(const short8*)(Wvbf + (size_t)(j * 16 + l15) * 64 + kk * 32 + g * 8);
#pragma unroll
                for (int ti = 0; ti < 2; ++ti)
                    acc[ti][j] = MFMA16(afr[kk][ti], bf, acc[ti][j]);
            }
#pragma unroll
        for (int ti = 0; ti < 2; ++ti)
#pragma unroll
            for (int j = 0; j < 4; ++j) {
                int col = j * 16 + l15, h1 = col >> 3, d1 = col & 7;
#pragma unroll
                for (int r = 0; r < 4; r += 2) {
                    int s = ti * 16 + g * 4 + r;
                    ushort2 p; p.x = f2b(acc[ti][j][r] + bvc[j]); p.y = f2b(acc[ti][j][r + 1] + bvc[j]);
                    *(ushort2*)&Vb[w][h1 * 256 + d1 * 32 + s] = p;
                }
            }
    }

    // ======== phase 2: 8-head MFMA attention (all wave-private) ========
    const float SCALE = 0.35355339059327373f;   // 1/sqrt(8)
    short8 zfrag = {};
#pragma unroll
    for (int h = 0; h < 8; ++h) {
        short8 kf[2], qf[2];
#pragma unroll
        for (int si = 0; si < 2; ++si)
            kf[si] = (lane < 16) ? *(const short8*)&Kb[w][h * 256 + (si * 16 + l15) * 8] : zfrag;
#pragma unroll
        for (int ti = 0; ti < 2; ++ti)
            qf[ti] = (lane < 16) ? *(const short8*)&Qb[w][h * 256 + (ti * 16 + l15) * 8] : zfrag;
        f32x4 sc[2][2];
#pragma unroll
        for (int si = 0; si < 2; ++si)
#pragma unroll
            for (int ti = 0; ti < 2; ++ti)
                sc[si][ti] = MFMA16(kf[si], qf[ti], f32x4{});
        unsigned pq[2][2][2];
#pragma unroll
        for (int ti = 0; ti < 2; ++ti) {
            float e0[4], e1[4], sm = 0.f;
#pragma unroll
            for (int r = 0; r < 4; ++r) {
                e0[r] = __expf(sc[0][ti][r] * SCALE);
                e1[r] = __expf(sc[1][ti][r] * SCALE);
                sm += e0[r] + e1[r];
            }
            sm += __shfl_xor(sm, 16);
            sm += __shfl_xor(sm, 32);
            float inv = 1.f / sm;
            pq[0][ti][0] = (unsigned)f2b(e0[0] * inv) | ((unsigned)f2b(e0[1] * inv) << 16);
            pq[0][ti][1] = (unsigned)f2b(e0[2] * inv) | ((unsigned)f2b(e0[3] * inv) << 16);
            pq[1][ti][0] = (unsigned)f2b(e1[0] * inv) | ((unsigned)f2b(e1[1] * inv) << 16);
            pq[1][ti][1] = (unsigned)f2b(e1[2] * inv) | ((unsigned)f2b(e1[3] * inv) << 16);
        }
        short8 vf = *(const short8*)&Vb[w][h * 256 + (l15 & 7) * 32 + g * 8];
        int L0 = l15 + ((g & 1) << 5);
        int L1 = L0 + 16;
        bool s1 = (g >> 1) != 0;
#pragma unroll
        for (int ti = 0; ti < 2; ++ti) {
            unsigned a00 = __shfl(pq[0][ti][0], L0), a01 = __shfl(pq[0][ti][1], L0);
            unsigned a10 = __shfl(pq[1][ti][0], L0), a11 = __shfl(pq[1][ti][1], L0);
            unsigned b00 = __shfl(pq[0][ti][0], L1), b01 = __shfl(pq[0][ti][1], L1);
            unsigned b10 = __shfl(pq[1][ti][0], L1), b11 = __shfl(pq[1][ti][1], L1);
            union { unsigned uu[4]; short8 s8; } af;
            af.uu[0] = s1 ? a10 : a00; af.uu[1] = s1 ? a11 : a01;
            af.uu[2] = s1 ? b10 : b00; af.uu[3] = s1 ? b11 : b01;
            f32x4 pv = MFMA16(af.s8, vf, f32x4{});
            if (l15 < 8) {
#pragma unroll
                for (int r = 0; r < 4; ++r)
                    attb[w][(ti * 16 + g * 4 + r) * 72 + h * 8 + l15] = f2b(pv[r]);
            }
        }
    }

    // ======== phase 3: MFMA epilogue out = att @ Wo^T + bo (all 64 cols) ========
    short8 aof[2][2];
#pragma unroll
    for (int kk = 0; kk < 2; ++kk)
#pragma unroll
        for (int ti = 0; ti < 2; ++ti)
            aof[kk][ti] = *(const short8*)&attb[w][(ti * 16 + l15) * 72 + kk * 32 + g * 8];
    f32x4 co[2][4] = {};
#pragma unroll
    for (int kk = 0; kk < 2; ++kk)
#pragma unroll
        for (int j = 0; j < 4; ++j) {
            short8 bf = *(const short8*)(Wobf + (size_t)(j * 16 + l15) * 64 + kk * 32 + g * 8);
#pragma unroll
            for (int ti = 0; ti < 2; ++ti)
                co[ti][j] = MFMA16(aof[kk][ti], bf, co[ti][j]);
        }
#pragma unroll
    for (int ti = 0; ti < 2; ++ti)
#pragma unroll
        for (int j = 0; j < 4; ++j)
#pragma unroll
            for (int r = 0; r < 4; ++r)
                out[(size_t)b * TD + (ti * 16 + g * 4 + r) * 64 + j * 16 + l15] =
                    co[ti][j][r] + boc[j];
}

extern "C" void kernel_launch(void* const* d_in, const int* in_sizes, int n_in,
                              void* d_out, int out_size, void* d_ws, size_t ws_size,
                              hipStream_t stream) {
    const float* q   = (const float*)d_in[0];
    const float* k   = (const float*)d_in[1];
    const float* v   = (const float*)d_in[2];
    const float* emb = (const float*)d_in[3];
    const float* We  = (const float*)d_in[4];
    const float* be  = (const float*)d_in[5];
    const float* Wq  = (const float*)d_in[6];
    const float* bq  = (const float*)d_in[7];
    const float* Wk  = (const float*)d_in[8];
    const float* bk  = (const float*)d_in[9];
    const float* Wv  = (const float*)d_in[10];
    const float* bv  = (const float*)d_in[11];
    const float* Wo  = (const float*)d_in[12];
    const float* bo  = (const float*)d_in[13];

    float* ws = (float*)d_ws;
    ushort* qp    = (ushort*)ws;                          // 16 MB (bf16)
    ushort* WnT   = (ushort*)(ws + 4194304);              // 32 MB
    ushort* qdifb = (ushort*)(ws + 12582912);             // 16 MB
    float*  Cj    = ws + 16777216;                        // 4 MB
    float*  bn    = ws + 17825792;                        // 1 MB
    float*  s_g   = ws + 18087936;                        // 16 KB
    int*    perm  = (int*)(ws + 18092032);                // 16 KB
    float*  Cb    = ws + 18096128;                        // 2 KB
    ushort* embbf = (ushort*)(ws + 18096640);             // 256 KB
    ushort* WeTT  = (ushort*)(ws + 18162176);             // 256 KB
    ushort* Wkbf  = (ushort*)(ws + 18227712);             // 8 KB
    ushort* Wvbf  = (ushort*)(ws + 18229760);             // 8 KB
    ushort* Wobf  = (ushort*)(ws + 18231808);             // 8 KB
    float*  PRE   = ws + 18233856;                        // 4.25 MB (end ~78 MB)
    float*  outp  = (float*)d_out;

    k_prep <<<1728, 256, 0, stream>>>(emb, We, be, Wk, Wv, Wo,
                                      s_g, embbf, WeTT, Wkbf, Wvbf, Wobf, bn);
    k_pr   <<<1024, 256, 0, stream>>>(q, Wq, bq, qp, s_g, perm);
    k_csum <<<dim3(64, 8), 256, 0, stream>>>(qp, s_g, perm, Cj, Cb);
    k_pre  <<<64, 256, 0, stream>>>(Cj, PRE);
    k_combw<<<1536, 256, 0, stream>>>(qp, s_g, perm, PRE, Cb, qdifb,
                                      embbf, WeTT, WnT);
    k_fused<<<2048, 128, 0, stream>>>(k, v, qdifb, WnT, bn,
                                      Wkbf, bk, Wvbf, bv, Wobf, bo, outp);
}